// Round 4
// baseline (1415.800 us; speedup 1.0000x reference)
//
#include <hip/hip_runtime.h>

#define BB 16
#define HH 512
#define ROWLEN 1536   // W*C
#define KK 51
#define RR 25

// chunk-level XOR swizzle: spreads stride-4-chunk lane patterns over all 8
// bank groups; bijective within each 64-chunk block (only low 3 bits change).
__device__ __forceinline__ int sq(int q) { return q ^ ((q >> 3) & 7); }

// ---------------- K0: reduce 2D kernel to 1D weights (g[i] = row sum) -------
__global__ void k_weights(const float* __restrict__ k2d, float* __restrict__ g) {
    int i = threadIdx.x;
    if (i < KK) {
        float s = 0.f;
        for (int j = 0; j < KK; ++j) s += k2d[i * KK + j];
        g[i] = s;
    }
}

// ---------------- H-pass: 51-tap conv along w, flat-index formulation -------
// out[f] = sum_j g[j] * in[f + 3*(j-25)]  (f = w*3+c flat index; per-channel
// taps have flat stride 3). 4 rows/block, 384 threads = 4 rows x 96 strips of
// 16 flat cols. One b128 read (4 flats) feeds one tap for each of ~5 of the
// thread's 16 accumulators. LDS row = 80 pad | 1536 | 80 pad = 1696 floats =
// 424 chunks, XOR-swizzled so lane chunk-stride 4 covers all 8 bank groups.
#define HROW 1696
#define HROWQ 424
template<bool U8>
__global__ __launch_bounds__(384) void k_hconv(const void* __restrict__ srcv,
                                               float* __restrict__ dst,
                                               const float* __restrict__ gsrc) {
    __shared__ __align__(16) float pl[4 * HROW];
    const int t = threadIdx.x;
    const int row0 = blockIdx.x * 4;             // first of 4 rows (b*512+h)

    float gw[KK];
    #pragma unroll
    for (int i = 0; i < KK; ++i) gw[i] = gsrc[i];   // uniform -> scalar regs

    // ---- load 4 rows into swizzled LDS ----
    if (U8) {
        const int r = t / 96, s = t % 96;            // 16 bytes per thread
        const uint4 d = *(const uint4*)((const unsigned char*)srcv
                          + (size_t)(row0 + r) * ROWLEN + 16 * s);
        const unsigned int w4[4] = {d.x, d.y, d.z, d.w};
        float* rowp = &pl[r * HROW];
        #pragma unroll
        for (int cq = 0; cq < 4; ++cq) {
            const unsigned int wd = w4[cq];
            float4 f;
            f.x = (float)(wd & 0xffu);         f.y = (float)((wd >> 8) & 0xffu);
            f.z = (float)((wd >> 16) & 0xffu); f.w = (float)((wd >> 24) & 0xffu);
            *(float4*)&rowp[4 * sq(20 + 4 * s + cq)] = f;
        }
    } else {
        #pragma unroll
        for (int i = 0; i < 4; ++i) {
            const int m = t + 384 * i;               // chunk id 0..1535
            const int r = m / 384, cc = m % 384;
            const float4 f = *(const float4*)((const float*)srcv
                               + (size_t)(row0 + r) * ROWLEN + 4 * cc);
            *(float4*)&pl[r * HROW + 4 * sq(20 + cc)] = f;
        }
    }
    __syncthreads();

    // ---- reflect halos: w=-j <-> w=j, w=511+j <-> 511-j (j=1..25), per c ----
    #pragma unroll
    for (int it = 0; it < 2; ++it) {
        const int item = t + it * 384;
        if (item < 600) {
            const int r = item / 150, k = item % 150;
            float* rowp = &pl[r * HROW];
            int edst, esrc;
            if (k < 75) {
                const int j = k / 3 + 1, c = k % 3;
                edst = 80 - 3 * j + c;  esrc = 80 + 3 * j + c;
            } else {
                const int k2 = k - 75;
                const int j = k2 / 3 + 1, c = k2 % 3;
                edst = 80 + (511 + j) * 3 + c;  esrc = 80 + (511 - j) * 3 + c;
            }
            const float v = rowp[4 * sq(esrc >> 2) + (esrc & 3)];
            rowp[4 * sq(edst >> 2) + (edst & 3)] = v;
        }
    }
    __syncthreads();

    // ---- compute: 16 consecutive flat outputs per thread ----
    const int r = t / 96, s = t % 96;                // strip f0 = 16*s
    const float* rowp = &pl[r * HROW];
    float acc[16];
    #pragma unroll
    for (int k = 0; k < 16; ++k) acc[k] = 0.f;
    #pragma unroll
    for (int u = 1; u < 44; ++u) {                   // chunks q = 4s+u
        const float4 v4 = *(const float4*)&rowp[4 * sq(4 * s + u)];
        #pragma unroll
        for (int m = 0; m < 4; ++m) {
            const int rel = -80 + 4 * u + m;         // flat offset from f0
            const float v = (&v4.x)[m];
            #pragma unroll
            for (int jj = 0; jj < KK; ++jj) {
                const int k = rel + 75 - 3 * jj;     // target accumulator
                if (k >= 0 && k < 16) acc[k] += gw[jj] * v;
            }
        }
    }
    const size_t ob = (size_t)(row0 + r) * ROWLEN + 16 * s;
    #pragma unroll
    for (int k = 0; k < 4; ++k) {
        float4 o;
        o.x = acc[4*k]; o.y = acc[4*k+1]; o.z = acc[4*k+2]; o.w = acc[4*k+3];
        *(float4*)&dst[ob + 4 * k] = o;
    }
}

// ---------------- V-pass: 51-tap conv along h + fused epilogue --------------
// Tile: 64 flat cols x 128 output rows (+50 halo). 256 threads = 16 col-groups
// (4 cols each, float4) x 16 row-groups (8 rows each): 32 outputs/thread, one
// b128 row-read feeds 4 col-accumulators for up to 8 rows (1:4.7 LDS:VALU).
// MODE 0: blur -> blurio (d_out as scratch), mask -> mask8.
// MODE 1: soft-mask; read img + blur (from blurio), write final to blurio.
#define FW 64
#define HC 128
#define VROWS 178    // HC + 2*RR

template<int MODE>
__global__ __launch_bounds__(256) void k_vconv(const float* __restrict__ src,
                                               const float* __restrict__ img,
                                               float* blurio,
                                               unsigned char* __restrict__ mask8,
                                               const float* __restrict__ gsrc) {
    __shared__ __align__(16) float tile[VROWS * FW];
    const int t  = threadIdx.x;
    const int cg = t & 15;               // col group: cols 4*cg..4*cg+3
    const int rg = t >> 4;               // row group: rows rg*8..rg*8+7
    const int bid = blockIdx.x;
    const int wcB = bid % 24;
    const int hB  = (bid / 24) & 3;
    const int b   = bid / 96;
    const int wc0 = wcB * 64;
    const int h0  = hB * HC;

    float gw[KK];
    #pragma unroll
    for (int i = 0; i < KK; ++i) gw[i] = gsrc[i];

    const size_t imgbase = (size_t)b * HH * ROWLEN;

    // ---- load tile (178 rows x 16 chunks) with reflect on h ----
    #pragma unroll
    for (int i = 0; i < 12; ++i) {
        const int m = t + 256 * i;
        if (m < VROWS * 16) {
            const int r = m >> 4, cc = m & 15;
            int hs = h0 - RR + r;
            hs = hs < 0 ? -hs : hs;
            hs = hs > 511 ? 1022 - hs : hs;
            *(float4*)&tile[r * FW + 4 * cc] =
                *(const float4*)&src[imgbase + (size_t)hs * ROWLEN + wc0 + 4 * cc];
        }
    }
    __syncthreads();

    float acc[8][4];
    #pragma unroll
    for (int a = 0; a < 8; ++a)
        #pragma unroll
        for (int m = 0; m < 4; ++m) acc[a][m] = 0.f;

    const float* base = &tile[(rg * 8) * FW + 4 * cg];
    #pragma unroll
    for (int jj = 0; jj < 58; ++jj) {
        const float4 v4 = *(const float4*)(base + jj * FW);
        #pragma unroll
        for (int a = 0; a < 8; ++a) {
            const int tap = jj - a;
            if (tap >= 0 && tap < KK) {
                acc[a][0] += gw[tap] * v4.x;
                acc[a][1] += gw[tap] * v4.y;
                acc[a][2] += gw[tap] * v4.z;
                acc[a][3] += gw[tap] * v4.w;
            }
        }
    }

    // ---- fused epilogue ----
    #pragma unroll
    for (int a = 0; a < 8; ++a) {
        const int hh = h0 + rg * 8 + a;
        const size_t idx = imgbase + (size_t)hh * ROWLEN + wc0 + 4 * cg;
        const float4 x4 = *(const float4*)&img[idx];
        if (MODE == 0) {
            float4 bl;
            bl.x = acc[a][0]; bl.y = acc[a][1]; bl.z = acc[a][2]; bl.w = acc[a][3];
            *(float4*)&blurio[idx] = bl;
            unsigned int mw = 0;
            mw |= (fabsf(x4.x - bl.x) * 255.0f > 10.0f) ? 1u : 0u;
            mw |= (fabsf(x4.y - bl.y) * 255.0f > 10.0f) ? (1u << 8) : 0u;
            mw |= (fabsf(x4.z - bl.z) * 255.0f > 10.0f) ? (1u << 16) : 0u;
            mw |= (fabsf(x4.w - bl.w) * 255.0f > 10.0f) ? (1u << 24) : 0u;
            *(unsigned int*)&mask8[idx] = mw;
        } else {
            const float4 bl4 = *(const float4*)&blurio[idx];
            float4 o;
            const float* xp = &x4.x; const float* bp = &bl4.x; float* op = &o.x;
            #pragma unroll
            for (int m = 0; m < 4; ++m) {
                const float x = xp[m];
                const float sharp = fminf(fmaxf(x + 0.5f * (x - bp[m]), 0.f), 1.f);
                op[m] = x + acc[a][m] * (sharp - x);
            }
            *(float4*)&blurio[idx] = o;
        }
    }
}

// ---------------------------------------------------------------------------
extern "C" void kernel_launch(void* const* d_in, const int* in_sizes, int n_in,
                              void* d_out, int out_size, void* d_ws, size_t ws_size,
                              hipStream_t stream) {
    (void)in_sizes; (void)n_in; (void)out_size; (void)ws_size;
    const float* img = (const float*)d_in[0];
    const float* k2d = (const float*)d_in[1];
    float* out = (float*)d_out;

    char* ws = (char*)d_ws;
    float* g = (float*)ws;                                       // 51 floats
    float* tbuf = (float*)(ws + 256);                            // 50.33 MB
    unsigned char* mask8 =
        (unsigned char*)(ws + 256 + (size_t)BB * HH * ROWLEN * 4); // 12.58 MB

    const int nhblk = BB * HH / 4;        // 2048
    const int nvblk = BB * 4 * 24;        // 1536

    k_weights<<<1, 64, 0, stream>>>(k2d, g);
    // P1: H-blur img -> tbuf
    k_hconv<false><<<nhblk, 384, 0, stream>>>((const void*)img, tbuf, g);
    // P2: V-blur tbuf -> blur (into d_out) + mask8
    k_vconv<0><<<nvblk, 256, 0, stream>>>(tbuf, img, out, mask8, g);
    // P3: H-blur mask8 -> tbuf
    k_hconv<true><<<nhblk, 384, 0, stream>>>((const void*)mask8, tbuf, g);
    // P4: V-blur tbuf -> soft mask, fused blend -> d_out
    k_vconv<1><<<nvblk, 256, 0, stream>>>(tbuf, img, out, mask8, g);
}

// Round 5
// 172.161 us; speedup vs baseline: 8.2237x; 8.2237x over previous
//
#include <hip/hip_runtime.h>

#define BB 16
#define HH 512
#define ROWLEN 1536   // W*C
#define KK 51
#define RR 25

// chunk-level XOR swizzle (involution): spreads strided chunk patterns over
// all 8 bank groups; bijective (only low 3 bits change).
__device__ __forceinline__ int sq(int q) { return q ^ ((q >> 3) & 7); }

// ---------------- K0: reduce 2D kernel to 1D weights (g[i] = row sum) -------
__global__ void k_weights(const float* __restrict__ k2d, float* __restrict__ g) {
    int i = threadIdx.x;
    if (i < KK) {
        float s = 0.f;
        for (int j = 0; j < KK; ++j) s += k2d[i * KK + j];
        g[i] = s;
    }
}

// ---------------- H-pass: 51-tap conv along w, per channel ------------------
// 4 rows/block, 384 threads = 12 (row,channel) planes x 32 lanes; 16 outputs
// per thread. Plane element e = w+25 (w in [-25,536]), stored chunk-swizzled:
// float addr = plane*576 + 4*sq(e>>2) + (e&3). Compute reads 17 ds_read_b128
// per thread (chunks 4l+v, v=0..16); value j=4v+m (e=16l+j) feeds accs
// a in [j-50, j] ∩ [0,16): 816 FMAs, all compile-time indexed.
#define PSTR 576     // floats per plane = 144 chunks (multiple of 8)
template<bool U8>
__global__ __launch_bounds__(384, 6) void k_hconv(const void* __restrict__ srcv,
                                                  float* __restrict__ dst,
                                                  const float* __restrict__ gsrc) {
    __shared__ __align__(16) float pl[12 * PSTR];
    const int t = threadIdx.x;
    const int row0 = blockIdx.x * 4;             // first of 4 rows (b*512+h)

    float gw[KK];
    #pragma unroll
    for (int i = 0; i < KK; ++i) gw[i] = gsrc[i];   // uniform -> scalar regs

    // ---- load 4 rows, de-interleave into swizzled planes ----
    #pragma unroll
    for (int it = 0; it < 2; ++it) {
        const int m = t + it * 384;
        if (m < 512) {
            const int r = m >> 7, u = m & 127;       // 12 values = 4 pixels
            const size_t rb = (size_t)(row0 + r) * ROWLEN;
            float f[12];
            if (U8) {
                const unsigned char* s8 = (const unsigned char*)srcv + rb + 12 * u;
                unsigned int ww[3];
                ww[0] = *(const unsigned int*)(s8);
                ww[1] = *(const unsigned int*)(s8 + 4);
                ww[2] = *(const unsigned int*)(s8 + 8);
                #pragma unroll
                for (int k = 0; k < 12; ++k)
                    f[k] = (float)((ww[k >> 2] >> ((k & 3) * 8)) & 0xffu);
            } else {
                const float* sf = (const float*)srcv + rb + 12 * u;
                *(float4*)&f[0] = *(const float4*)(sf);
                *(float4*)&f[4] = *(const float4*)(sf + 4);
                *(float4*)&f[8] = *(const float4*)(sf + 8);
            }
            #pragma unroll
            for (int i = 0; i < 4; ++i)
                #pragma unroll
                for (int c = 0; c < 3; ++c) {
                    const int e = RR + 4 * u + i;    // element of plane
                    pl[(r * 3 + c) * PSTR + 4 * sq(e >> 2) + (e & 3)] = f[3 * i + c];
                }
        }
    }
    __syncthreads();

    // ---- reflect halos (np.pad 'reflect'): 12 planes x 50 elements ----
    #pragma unroll
    for (int it = 0; it < 2; ++it) {
        const int item = t + it * 384;
        if (item < 600) {
            const int p = item / 50, k = item % 50;
            int edst, esrc;
            if (k < 25) { edst = 24 - k;  esrc = 26 + k; }       // w=-(k+1) <- w=k+1
            else { const int k2 = k - 25; edst = 537 + k2; esrc = 535 - k2; } // w=512+k2 <- w=510-k2
            float* pb = &pl[p * PSTR];
            pb[4 * sq(edst >> 2) + (edst & 3)] = pb[4 * sq(esrc >> 2) + (esrc & 3)];
        }
    }
    __syncthreads();

    // ---- compute: 16 consecutive pixels of one (row,channel) per thread ----
    const int p = t >> 5;             // plane 0..11
    const int l = t & 31;             // lane within plane; w0 = 16*l
    const float* pb = &pl[p * PSTR];
    float acc[16];
    #pragma unroll
    for (int a = 0; a < 16; ++a) acc[a] = 0.f;
    #pragma unroll
    for (int v = 0; v < 17; ++v) {
        const float4 v4 = *(const float4*)&pb[4 * sq(4 * l + v)];
        #pragma unroll
        for (int m = 0; m < 4; ++m) {
            const int j = 4 * v + m;               // tap for acc a is j-a
            const float val = (&v4.x)[m];
            #pragma unroll
            for (int a = 0; a < 16; ++a) {
                const int tp = j - a;
                if (tp >= 0 && tp < KK) acc[a] += gw[tp] * val;
            }
        }
    }
    const int r = p / 3, c = p % 3;
    const size_t rb = (size_t)(row0 + r) * ROWLEN;
    const int w0 = l << 4;
    #pragma unroll
    for (int a = 0; a < 16; ++a)
        dst[rb + (size_t)(w0 + a) * 3 + c] = acc[a];
}

// ---------------- V-pass: 51-tap conv along h + fused epilogue --------------
// Tile: 64 flat cols x 128 output rows (+50 halo). 256 threads = 16 col-groups
// (4 cols each, float4) x 16 row-groups (8 rows each): 32 outputs/thread, one
// b128 row-read feeds 4 col-accumulators for up to 8 rows.
// MODE 0: blur -> blurio (d_out as scratch), mask -> mask8.
// MODE 1: soft-mask; read img + blur (from blurio), write final to blurio.
#define FW 64
#define HC 128
#define VROWS 178    // HC + 2*RR

template<int MODE>
__global__ __launch_bounds__(256) void k_vconv(const float* __restrict__ src,
                                               const float* __restrict__ img,
                                               float* blurio,
                                               unsigned char* __restrict__ mask8,
                                               const float* __restrict__ gsrc) {
    __shared__ __align__(16) float tile[VROWS * FW];
    const int t  = threadIdx.x;
    const int cg = t & 15;               // col group: cols 4*cg..4*cg+3
    const int rg = t >> 4;               // row group: rows rg*8..rg*8+7
    const int bid = blockIdx.x;
    const int wcB = bid % 24;
    const int hB  = (bid / 24) & 3;
    const int b   = bid / 96;
    const int wc0 = wcB * 64;
    const int h0  = hB * HC;

    float gw[KK];
    #pragma unroll
    for (int i = 0; i < KK; ++i) gw[i] = gsrc[i];

    const size_t imgbase = (size_t)b * HH * ROWLEN;

    // ---- load tile (178 rows x 16 chunks) with reflect on h ----
    #pragma unroll
    for (int i = 0; i < 12; ++i) {
        const int m = t + 256 * i;
        if (m < VROWS * 16) {
            const int r = m >> 4, cc = m & 15;
            int hs = h0 - RR + r;
            hs = hs < 0 ? -hs : hs;
            hs = hs > 511 ? 1022 - hs : hs;
            *(float4*)&tile[r * FW + 4 * cc] =
                *(const float4*)&src[imgbase + (size_t)hs * ROWLEN + wc0 + 4 * cc];
        }
    }
    __syncthreads();

    float acc[8][4];
    #pragma unroll
    for (int a = 0; a < 8; ++a)
        #pragma unroll
        for (int m = 0; m < 4; ++m) acc[a][m] = 0.f;

    const float* base = &tile[(rg * 8) * FW + 4 * cg];
    #pragma unroll
    for (int jj = 0; jj < 58; ++jj) {
        const float4 v4 = *(const float4*)(base + jj * FW);
        #pragma unroll
        for (int a = 0; a < 8; ++a) {
            const int tap = jj - a;
            if (tap >= 0 && tap < KK) {
                acc[a][0] += gw[tap] * v4.x;
                acc[a][1] += gw[tap] * v4.y;
                acc[a][2] += gw[tap] * v4.z;
                acc[a][3] += gw[tap] * v4.w;
            }
        }
    }

    // ---- fused epilogue ----
    #pragma unroll
    for (int a = 0; a < 8; ++a) {
        const int hh = h0 + rg * 8 + a;
        const size_t idx = imgbase + (size_t)hh * ROWLEN + wc0 + 4 * cg;
        const float4 x4 = *(const float4*)&img[idx];
        if (MODE == 0) {
            float4 bl;
            bl.x = acc[a][0]; bl.y = acc[a][1]; bl.z = acc[a][2]; bl.w = acc[a][3];
            *(float4*)&blurio[idx] = bl;
            unsigned int mw = 0;
            mw |= (fabsf(x4.x - bl.x) * 255.0f > 10.0f) ? 1u : 0u;
            mw |= (fabsf(x4.y - bl.y) * 255.0f > 10.0f) ? (1u << 8) : 0u;
            mw |= (fabsf(x4.z - bl.z) * 255.0f > 10.0f) ? (1u << 16) : 0u;
            mw |= (fabsf(x4.w - bl.w) * 255.0f > 10.0f) ? (1u << 24) : 0u;
            *(unsigned int*)&mask8[idx] = mw;
        } else {
            const float4 bl4 = *(const float4*)&blurio[idx];
            float4 o;
            const float* xp = &x4.x; const float* bp = &bl4.x; float* op = &o.x;
            #pragma unroll
            for (int m = 0; m < 4; ++m) {
                const float x = xp[m];
                const float sharp = fminf(fmaxf(x + 0.5f * (x - bp[m]), 0.f), 1.f);
                op[m] = x + acc[a][m] * (sharp - x);
            }
            *(float4*)&blurio[idx] = o;
        }
    }
}

// ---------------------------------------------------------------------------
extern "C" void kernel_launch(void* const* d_in, const int* in_sizes, int n_in,
                              void* d_out, int out_size, void* d_ws, size_t ws_size,
                              hipStream_t stream) {
    (void)in_sizes; (void)n_in; (void)out_size; (void)ws_size;
    const float* img = (const float*)d_in[0];
    const float* k2d = (const float*)d_in[1];
    float* out = (float*)d_out;

    char* ws = (char*)d_ws;
    float* g = (float*)ws;                                       // 51 floats
    float* tbuf = (float*)(ws + 256);                            // 50.33 MB
    unsigned char* mask8 =
        (unsigned char*)(ws + 256 + (size_t)BB * HH * ROWLEN * 4); // 12.58 MB

    const int nhblk = BB * HH / 4;        // 2048
    const int nvblk = BB * 4 * 24;        // 1536

    k_weights<<<1, 64, 0, stream>>>(k2d, g);
    // P1: H-blur img -> tbuf
    k_hconv<false><<<nhblk, 384, 0, stream>>>((const void*)img, tbuf, g);
    // P2: V-blur tbuf -> blur (into d_out) + mask8
    k_vconv<0><<<nvblk, 256, 0, stream>>>(tbuf, img, out, mask8, g);
    // P3: H-blur mask8 -> tbuf
    k_hconv<true><<<nhblk, 384, 0, stream>>>((const void*)mask8, tbuf, g);
    // P4: V-blur tbuf -> soft mask, fused blend -> d_out
    k_vconv<1><<<nvblk, 256, 0, stream>>>(tbuf, img, out, mask8, g);
}